// Round 1
// 668.472 us; speedup vs baseline: 1.2545x; 1.2545x over previous
//
#include <hip/hip_runtime.h>
#include <math.h>

// 16-qubit statevector, 512 batch, float2[512][65536] in d_ws (256 MiB).
// Bit convention: wire w <-> bit (15-w). 4 state passes + tail.
// Round-N changes (latency theory: all kernels ~5x off both rooflines, occ 30%):
//  * qs_prep: all 14 composed 2x2 gates baked once into a 448B table (stored in
//    d_out scratch, overwritten by qs_tail) -> removes per-thread sincos/gmul.
//  * qs_p5: single-phase, LDS-free. S0..S4 share one reg-parity class S4l
//    (S_j = parity(ul_j..ul8) = parity(r) ^ parity(tid&M)); X01/X12/X23 via
//    lane-xor ds_swizzle dots; X34 = reg^1 x lane^8. No barriers, no LDS.
//  * wave reductions via immediate ds_swizzle butterfly + readlane (no per-
//    shuffle VALU address setup); uniform result feeds the atomics.
//  * Gray addressing strength-reduced: g(B|R)=g(B)^g(R) -> 1 XOR per element.
// Gate/measurement algebra identical to the verified round-3 scheme.

#define NT 256
#define ACCS 40
#define BSZQ 512

struct C2 { float r, i; };
struct G1Q { C2 a, b, c, d; };

__device__ __forceinline__ C2 cmul(C2 x, C2 y){ return C2{ x.r*y.r - x.i*y.i, x.r*y.i + x.i*y.r }; }
__device__ __forceinline__ C2 cadd(C2 x, C2 y){ return C2{ x.r + y.r, x.i + y.i }; }
__device__ __forceinline__ G1Q mkRX(float th){
  float cc = cosf(0.5f*th), ss = sinf(0.5f*th);
  return G1Q{ C2{cc,0.f}, C2{0.f,-ss}, C2{0.f,-ss}, C2{cc,0.f} };
}
__device__ __forceinline__ G1Q mkRY(float th){
  float cc = cosf(0.5f*th), ss = sinf(0.5f*th);
  return G1Q{ C2{cc,0.f}, C2{-ss,0.f}, C2{ss,0.f}, C2{cc,0.f} };
}
__device__ __forceinline__ G1Q gmul(G1Q A, G1Q B){ // A*B, B applied first
  return G1Q{ cadd(cmul(A.a,B.a), cmul(A.b,B.c)),
              cadd(cmul(A.a,B.b), cmul(A.b,B.d)),
              cadd(cmul(A.c,B.a), cmul(A.d,B.c)),
              cadd(cmul(A.c,B.b), cmul(A.d,B.d)) };
}

// LDS swizzles for p1/p2/p4 staging (proven conflict-minimal).
__device__ __forceinline__ int swzA(int l){ return (l & 0xFF0) | (((l>>4) ^ l) & 15); }
__device__ __forceinline__ int swzB(int l){ return (l & 0xFF0) | (((l>>8) ^ l) & 15); }

// Immediate-pattern lane xor (ds_swizzle BitMode: offset = xor<<10 | and 0x1F).
template<int M>
__device__ __forceinline__ float swzx(float x){
  return __int_as_float(__builtin_amdgcn_ds_swizzle(__float_as_int(x), (M<<10)|0x1F));
}
// Full-wave sum: 5 xor-butterfly steps within 32-lane halves + readlane(0)+readlane(32).
// Result is wave-uniform. All 64 lanes must be active.
__device__ __forceinline__ float wsum(float x){
  x += swzx<1>(x);
  x += swzx<2>(x);
  x += swzx<4>(x);
  x += swzx<8>(x);
  x += swzx<16>(x);
  return __int_as_float(__builtin_amdgcn_readlane(__float_as_int(x), 0)) +
         __int_as_float(__builtin_amdgcn_readlane(__float_as_int(x), 32));
}

__device__ __forceinline__ G1Q loadG(const float* __restrict__ gt, int i){
  const float4* p = (const float4*)(gt + i*8);
  float4 u = p[0], w = p[1];
  return G1Q{ C2{u.x,u.y}, C2{u.z,u.w}, C2{w.x,w.y}, C2{w.z,w.w} };
}

__device__ __forceinline__ void greg16(float2* v, const G1Q g, const int q){
  const int bq = 1<<q;
  #pragma unroll
  for (int r=0;r<16;r++){
    if (r & bq) continue;
    float2 a0 = v[r], a1 = v[r|bq];
    v[r].x    = g.a.r*a0.x - g.a.i*a0.y + g.b.r*a1.x - g.b.i*a1.y;
    v[r].y    = g.a.r*a0.y + g.a.i*a0.x + g.b.r*a1.y + g.b.i*a1.x;
    v[r|bq].x = g.c.r*a0.x - g.c.i*a0.y + g.d.r*a1.x - g.d.i*a1.y;
    v[r|bq].y = g.c.r*a0.y + g.c.i*a0.x + g.d.r*a1.y + g.d.i*a1.x;
  }
}
__device__ __forceinline__ void creg16(float2* v, const int qc, const int qt){
  #pragma unroll
  for (int r=0;r<16;r++){
    if ((r & (1<<qc)) && !(r & (1<<qt))){
      float2 tmp = v[r]; v[r] = v[r|(1<<qt)]; v[r|(1<<qt)] = tmp;
    }
  }
}
__device__ __forceinline__ float xdot16(const float2* v, const int m){
  float s = 0.f;
  #pragma unroll
  for (int r=0;r<16;r++) s += v[r].x*v[r^m].x + v[r].y*v[r^m].y;
  return s;
}

// ---------------- P0: bake the 14 composed gates (1 thread) ----------------
__global__ void qs_prep(const float* __restrict__ ra, const float* __restrict__ trx,
                        const float* __restrict__ tryv, float* __restrict__ gt){
  if (threadIdx.x != 0) return;
  float trx0 = trx[0];
  G1Q RX0 = mkRX(trx0);
  G1Q g[14];
  g[0]  = gmul(RX0, gmul(mkRY(ra[19]), mkRX(ra[3])));   // p1 alpha q0 (w15)
  g[1]  = mkRX(trx0 + ra[6]);                           // p1 alpha q1
  g[2]  = mkRX(trx0 + ra[9]);                           // p1 alpha q2
  g[3]  = mkRX(trx0 + ra[12]);                          // p1 alpha q3
  g[4]  = mkRX(trx0 + ra[15]);                          // p1 beta q0
  g[5]  = mkRX(trx0 + ra[18]);                          // p1 beta q1
  g[6]  = RX0;                                          // shared
  g[7]  = gmul(RX0, mkRY(ra[4]));                       // p2 A q3 (w4)
  g[8]  = mkRY(ra[1]);                                  // p2 A q2 (w5 RY)
  g[9]  = gmul(RX0, mkRY(ra[7]));                       // p2 B q0 (w3)
  g[10] = gmul(RX0, mkRY(ra[10]));                      // p2 B q1 (w2)
  g[11] = gmul(RX0, mkRY(ra[13]));                      // p2 B q2 (w1)
  g[12] = gmul(RX0, gmul(mkRY(ra[16]), mkRX(ra[0])));   // p2 B q3 (w0)
  g[13] = gmul(mkRX(trx[1]), mkRY(tryv[0]));            // U for p4/p5
  for (int i=0;i<14;i++){
    gt[i*8+0]=g[i].a.r; gt[i*8+1]=g[i].a.i;
    gt[i*8+2]=g[i].b.r; gt[i*8+3]=g[i].b.i;
    gt[i*8+4]=g[i].c.r; gt[i*8+5]=g[i].c.i;
    gt[i*8+6]=g[i].d.r; gt[i*8+7]=g[i].d.i;
  }
}

// ---------------- P1 (L tile): input->complex, random-layer L gates + RX0 ----------------
__global__ __launch_bounds__(NT) void qs_p1(const float* __restrict__ x, const float* __restrict__ gt,
                                            float2* __restrict__ psi, float* __restrict__ acc){
  __shared__ __align__(16) float2 s[4096];
  int b = blockIdx.x >> 4, t = blockIdx.x & 15;
  int tid = threadIdx.x;
  if (t == 0 && tid < ACCS) acc[b*ACCS + tid] = 0.f;
  float2 v[16];
  // phase alpha: regs = bits 0..3, threads = bits 4..11
  const float4* xb = (const float4*)(x + (size_t)b*65536 + t*4096 + tid*16);
  #pragma unroll
  for (int q=0;q<4;q++){
    float4 f = xb[q];
    v[4*q+0] = make_float2(f.x, 0.f);
    v[4*q+1] = make_float2(f.y, 0.f);
    v[4*q+2] = make_float2(f.z, 0.f);
    v[4*q+3] = make_float2(f.w, 0.f);
  }
  greg16(v, loadG(gt,0), 0);   // w15
  greg16(v, loadG(gt,1), 1);   // w14
  greg16(v, loadG(gt,2), 2);   // w13
  greg16(v, loadG(gt,3), 3);   // w12
  #pragma unroll
  for (int j=0;j<16;j++) s[swzA(j | (tid<<4))] = v[j];
  __syncthreads();
  // phase beta: regs = bits 4..7; tid: b0..3 = bits 0..3, b4..7 = bits 8..11
  #pragma unroll
  for (int r=0;r<16;r++) v[r] = s[swzA((tid&15) | (r<<4) | ((tid>>4)<<8))];
  creg16(v, 1, 0);                       // C(w10->w11)
  creg16(v, 2, 1);                       // C(w9->w10)
  creg16(v, 3, 2);                       // C(w8->w9)
  {                                      // C(w7->w8): ctrl bit8 = tid bit4, tgt bit7 = r3
    bool c8 = (tid & 16);
    #pragma unroll
    for (int r=0;r<8;r++){
      float2 lo = v[r], hi = v[r|8];
      v[r]   = c8 ? hi : lo;
      v[r|8] = c8 ? lo : hi;
    }
  }
  greg16(v, loadG(gt,4), 0);     // w11
  greg16(v, loadG(gt,5), 1);     // w10
  G1Q G6 = loadG(gt,6);
  greg16(v, G6, 2);              // w9
  greg16(v, G6, 3);              // w8
  float2* pbL = psi + (size_t)b*65536 + t*4096;
  #pragma unroll
  for (int r=0;r<16;r++) pbL[(tid&15) | (r<<4) | ((tid>>4)<<8)] = v[r];
}

// ---------------- P2 (H tile): random-layer H gates + RX0 on wires 0..7 ----------------
__global__ __launch_bounds__(NT) void qs_p2(float2* __restrict__ psi, const float* __restrict__ gt){
  __shared__ __align__(16) float2 s[4096];
  int b = blockIdx.x >> 4, t = blockIdx.x & 15;
  int tid = threadIdx.x;
  float2 v[16];
  float2* pb = psi + (size_t)b*65536;
  // phase A: regs = g8..11; tid: b0..3 = g0..3, b4..7 = g12..15
  #pragma unroll
  for (int r=0;r<16;r++)
    v[r] = pb[(tid&15) | (t<<4) | (r<<8) | ((tid>>4)<<12)];
  greg16(v, loadG(gt,7), 3);   // w4
  greg16(v, loadG(gt,8), 2);   // w5 (RY part)
  creg16(v, 1, 0);             // C(w6->w7)
  creg16(v, 2, 1);             // C(w5->w6)
  G1Q G6 = loadG(gt,6);
  greg16(v, G6, 2);            // w5
  greg16(v, G6, 1);            // w6
  greg16(v, G6, 0);            // w7
  #pragma unroll
  for (int r=0;r<16;r++) s[swzA((tid&15) | (r<<4) | ((tid>>4)<<8))] = v[r];
  __syncthreads();
  // phase B: regs = g12..15; tid: b0..3 = g0..3, b4..7 = g8..11
  #pragma unroll
  for (int r=0;r<16;r++) v[r] = s[swzA((tid&15) | ((tid>>4)<<4) | (r<<8))];
  greg16(v, loadG(gt,9), 0);    // w3
  greg16(v, loadG(gt,10), 1);   // w2
  greg16(v, loadG(gt,11), 2);   // w1
  greg16(v, loadG(gt,12), 3);   // w0
  #pragma unroll
  for (int r=0;r<16;r++)
    pb[(tid&15) | (t<<4) | ((tid>>4)<<8) | (r<<12)] = v[r];
}

// ---------------- P4 (H tile on y-frame, T folded into load/store addr) ----------------
// Phases A (y0..3) -> C (y12..15) -> B (y8..11). K as lane-swizzle CNOT in A.
__global__ __launch_bounds__(NT) void qs_p4(float2* __restrict__ psi, const float* __restrict__ gt,
                                            float* __restrict__ acc){
  __shared__ __align__(16) float2 s[4096];
  int b = blockIdx.x >> 4, t = blockIdx.x & 15;
  int tid = threadIdx.x;
  G1Q U = loadG(gt, 13);
  float2* pb = psi + (size_t)b*65536;
  float2 v[16];
  // ---- phase A: regs y0..3; tid: b0..3 = y12..15, b4..7 = y8..11 ----
  {
    int Y = (tid>>4) | ((tid&15)<<4);          // y8..15
    int XH = Y ^ (Y>>1);                       // x8..15
    int x7 = ((t>>3) ^ Y) & 1;                 // t3 ^ y8
    int runbase = (XH<<8) | (x7<<7) | (((t ^ (t>>1)) & 7) << 4);
    const float4* rp = (const float4*)(pb + runbase);
    float2 tmp[16];
    #pragma unroll
    for (int q=0;q<8;q++){
      float4 f = rp[q];
      tmp[2*q]   = make_float2(f.x, f.y);
      tmp[2*q+1] = make_float2(f.z, f.w);
    }
    // v[j] = tmp[alpha], j bitk = parity(alpha>>k) (^15 if t0)
    if (t & 1){
      v[15]=tmp[0];  v[14]=tmp[1];  v[12]=tmp[2];  v[13]=tmp[3];
      v[ 8]=tmp[4];  v[ 9]=tmp[5];  v[11]=tmp[6];  v[10]=tmp[7];
      v[ 0]=tmp[8];  v[ 1]=tmp[9];  v[ 3]=tmp[10]; v[ 2]=tmp[11];
      v[ 7]=tmp[12]; v[ 6]=tmp[13]; v[ 4]=tmp[14]; v[ 5]=tmp[15];
    } else {
      v[ 0]=tmp[0];  v[ 1]=tmp[1];  v[ 3]=tmp[2];  v[ 2]=tmp[3];
      v[ 7]=tmp[4];  v[ 6]=tmp[5];  v[ 4]=tmp[6];  v[ 5]=tmp[7];
      v[15]=tmp[8];  v[14]=tmp[9];  v[12]=tmp[10]; v[13]=tmp[11];
      v[ 8]=tmp[12]; v[ 9]=tmp[13]; v[11]=tmp[14]; v[10]=tmp[15];
    }
    // K = C(w15->w0): ctrl y0 (reg bit0), tgt y15 (lane bit3) -> lane-xor swap
    #pragma unroll
    for (int r=1;r<16;r+=2){
      v[r].x = swzx<8>(v[r].x);
      v[r].y = swzx<8>(v[r].y);
    }
    greg16(v, U, 0); greg16(v, U, 1); greg16(v, U, 2); greg16(v, U, 3); // w15,w14,w13,w12
    #pragma unroll
    for (int j=0;j<16;j++)
      s[swzB(j | ((tid>>4)<<4) | ((tid&15)<<8))] = v[j];
  }
  __syncthreads();
  float Xa, Xb, Xc, Xd;
  // ---- phase C: regs y12..15; tid: b0..3 = y0..3, b4..7 = y8..11 ----
  {
    #pragma unroll
    for (int r=0;r<16;r++)
      v[r] = s[swzB((tid&15) | ((tid>>4)<<4) | (r<<8))];
    greg16(v, U, 0); greg16(v, U, 1); greg16(v, U, 2); greg16(v, U, 3); // w3,w2,w1,w0
    creg16(v, 3, 2);  // chain1 C(w0->w1)
    creg16(v, 2, 1);  // C(w1->w2)
    creg16(v, 1, 0);  // C(w2->w3)
    Xa = xdot16(v, 8);   // X_w0 (y15)
    Xb = xdot16(v, 4);   // X_w1 (y14)
    Xc = xdot16(v, 2);   // X_w2 (y13)
    Xd = 0.f;            // <X_w0 X_w15> = y15 (reg) x y0 (lane bit0)
    #pragma unroll
    for (int r=0;r<16;r++)
      Xd += v[r].x * swzx<1>(v[r^8].x) + v[r].y * swzx<1>(v[r^8].y);
    __syncthreads();
    #pragma unroll
    for (int r=0;r<16;r++)
      s[swzB((tid&15) | ((tid>>4)<<4) | (r<<8))] = v[r];
  }
  __syncthreads();
  // ---- phase B: regs y8..11; tid: b0..3 = y0..3, b4..7 = y12..15 ----
  float Xe, Xf, Xg, Xh;
  {
    #pragma unroll
    for (int r=0;r<16;r++)
      v[r] = s[swzB((tid&15) | (r<<4) | ((tid>>4)<<8))];
    greg16(v, U, 0); greg16(v, U, 1); greg16(v, U, 2); greg16(v, U, 3); // w7,w6,w5,w4
    {                                  // C(w3->w4): ctrl y12 = tid bit4, tgt y11 = r3
      bool c12 = (tid & 16);
      #pragma unroll
      for (int r=0;r<8;r++){
        float2 lo = v[r], hi = v[r|8];
        v[r]   = c12 ? hi : lo;
        v[r|8] = c12 ? lo : hi;
      }
    }
    creg16(v, 3, 2);  // C(w4->w5)
    creg16(v, 2, 1);  // C(w5->w6)
    creg16(v, 1, 0);  // C(w6->w7)
    Xe = 0.f;         // X_w3 (y12 = lane bit4)
    #pragma unroll
    for (int r=0;r<16;r++)
      Xe += v[r].x * swzx<16>(v[r].x) + v[r].y * swzx<16>(v[r].y);
    Xf = xdot16(v, 8);   // X_w4
    Xg = xdot16(v, 4);   // X_w5
    Xh = xdot16(v, 2);   // X_w6
    // store, T folded: g(base|r<<8) = g(base) ^ ((r<<8)^(r<<7))
    int Bs = (tid&15) | (t<<4) | ((tid>>4)<<12);
    int Cs = Bs ^ (Bs>>1);
    #pragma unroll
    for (int r=0;r<16;r++)
      pb[Cs ^ ((r<<8) ^ (r<<7))] = v[r];
  }
  float vals[8] = {Xa, Xb, Xc, Xe, Xf, Xg, Xh, Xd};
  #pragma unroll
  for (int i=0;i<8;i++) vals[i] = wsum(vals[i]);
  if ((tid & 63) == 0){
    float* A = acc + b*ACCS;
    #pragma unroll
    for (int i=0;i<7;i++) atomicAdd(A+25+i, vals[i]);
    atomicAdd(A+32, vals[7]);
  }
}

// ---------------- P5 (L tile, read-only, single-phase, no LDS) ----------------
// Regs = ul4..7 (post-U after 4 greg16); lanes b0..3 = ul0..3, b4..7 = ul8..11.
// S_j (j=0..4) = sum over parity(ul_j..ul8)=1 = sel(parity(tid&M), totA-S4l, S4l),
// M in {0x1F,0x1E,0x1C,0x18,0x10} — all share the single reg-parity class S4l.
// X01/X12/X23 = lane-xor dots (masks 3/6/12); X34 = reg^1 x lane^8; X78 = reg^8 x lane^16.
__global__ __launch_bounds__(NT) void qs_p5(const float2* __restrict__ psi, const float* __restrict__ gt,
                                            float* __restrict__ acc){
  int b = blockIdx.x >> 4, t = blockIdx.x & 15;
  int tid = threadIdx.x;
  G1Q U = loadG(gt, 13);
  const float2* pb = psi + (size_t)b*65536;
  float2 v[16];
  // T-unfold gather, strength-reduced: addr(r) = g(Bv) ^ ((r<<4)^(r<<3))
  int Bv = (t<<12) | ((tid>>4)<<8) | (tid&15);
  int Cg = Bv ^ (Bv>>1);
  #pragma unroll
  for (int r=0;r<16;r++)
    v[r] = pb[Cg ^ ((r<<4) ^ (r<<3))];
  greg16(v, U, 0); greg16(v, U, 1); greg16(v, U, 2); greg16(v, U, 3); // w11..w8
  float totA=0.f, S4l=0.f, S5l=0.f, S6l=0.f, S7l=0.f;
  #pragma unroll
  for (int r=0;r<16;r++){
    float a2 = v[r].x*v[r].x + v[r].y*v[r].y;
    totA += a2;
    if (__popc(r)&1)    S4l += a2;
    if (__popc(r>>1)&1) S5l += a2;
    if (__popc(r>>2)&1) S6l += a2;
    if (__popc(r>>3)&1) S7l += a2;
  }
  float S4h = totA - S4l;
  float S0 = (__popc(tid & 0x1F)&1) ? S4h : S4l;   // parity(ul0..3,ul8)^parity(ul4..7)
  float S1 = (__popc(tid & 0x1E)&1) ? S4h : S4l;   // parity(ul1..8)
  float S2 = (__popc(tid & 0x1C)&1) ? S4h : S4l;   // parity(ul2..8)
  float S3 = (__popc(tid & 0x18)&1) ? S4h : S4l;   // parity(ul3..8)
  bool u8 = (tid & 16);
  float S4 = u8 ? S4h : S4l;                       // parity(ul4..8)
  float S5 = u8 ? totA - S5l : S5l;
  float S6 = u8 ? totA - S6l : S6l;
  float S7 = u8 ? totA - S7l : S7l;
  float S8 = u8 ? totA : 0.f;
  float K9  = (tid & 32) ? totA : 0.f;
  float K10 = (tid & 64) ? totA : 0.f;
  float K11 = (tid & 128)? totA : 0.f;
  float X45 = xdot16(v,3), X56 = xdot16(v,6), X67 = xdot16(v,12);
  float X01=0.f, X12=0.f, X23=0.f, X34=0.f, X78=0.f;
  #pragma unroll
  for (int r=0;r<16;r++){
    float vx = v[r].x, vy = v[r].y;
    X01 += vx*swzx<3>(vx)  + vy*swzx<3>(vy);            // flips ul0,ul1
    X12 += vx*swzx<6>(vx)  + vy*swzx<6>(vy);            // flips ul1,ul2
    X23 += vx*swzx<12>(vx) + vy*swzx<12>(vy);           // flips ul2,ul3
    X34 += vx*swzx<8>(v[r^1].x) + vy*swzx<8>(v[r^1].y); // ul3 (lane b3) x ul4 (reg b0)
    X78 += vx*swzx<16>(v[r^8].x) + vy*swzx<16>(v[r^8].y); // ul7 (reg b3) x ul8 (lane b4)
  }
  float vals[21] = {totA, S0,S1,S2,S3,S4,S5,S6,S7,S8, K9,K10,K11,
                    X01,X12,X23,X34,X45,X56,X67,X78};
  #pragma unroll
  for (int i=0;i<21;i++) vals[i] = wsum(vals[i]);
  if ((tid & 63) == 0){
    float* A = acc + b*ACCS;
    atomicAdd(A+0, vals[0]);
    #pragma unroll
    for (int p=0;p<12;p++) atomicAdd(A+1+p, vals[1+p]);
    if (t&1) atomicAdd(A+13, vals[0]);
    if (t&2) atomicAdd(A+14, vals[0]);
    if (t&4) atomicAdd(A+15, vals[0]);
    float zz = vals[0] - 2.f*vals[1];
    if (t&8) zz = -zz;
    atomicAdd(A+16, zz);
    #pragma unroll
    for (int j=0;j<8;j++) atomicAdd(A+17+j, vals[13+j]);
  }
}

// ---------------- Tail (unchanged, verified) ----------------
__global__ __launch_bounds__(256) void qs_tail(const float* __restrict__ acc, const float* __restrict__ tryv,
    const float* __restrict__ w1, const float* __restrict__ b1,
    const float* __restrict__ w2, const float* __restrict__ b2,
    const float* __restrict__ g1, const float* __restrict__ be1,
    const float* __restrict__ g2, const float* __restrict__ be2,
    const float* __restrict__ wh, const float* __restrict__ bh,
    float* __restrict__ out){
  int b = blockIdx.x * 256 + threadIdx.x;
  if (b >= BSZQ) return;
  const float* A = acc + b*ACCS;
  float tot = A[0];
  float inv = 1.f / tot;
  float Z[16], X[16];
  Z[0] = A[16] * inv;
  Z[1] = 1.f - 2.f*A[15]*inv;
  Z[2] = 1.f - 2.f*A[14]*inv;
  Z[3] = 1.f - 2.f*A[13]*inv;
  #pragma unroll
  for (int w=4; w<15; w++) Z[w] = 1.f - 2.f*A[1 + (15-w)]*inv;
  Z[15] = 1.f - 2.f*A[1]*inv;
  #pragma unroll
  for (int w=0; w<7; w++) X[w] = A[25+w]*inv;
  #pragma unroll
  for (int w=7; w<15; w++) X[w] = A[16 + (15-w)]*inv;
  X[15] = A[32]*inv;
  float th = tryv[1];
  float ct = cosf(th), st = sinf(th);
  float M4[16];
  #pragma unroll
  for (int w=0; w<16; w++) M4[w] = ct*Z[w] - st*X[w];
  float mu = 0.f;
  #pragma unroll
  for (int w=0; w<16; w++) mu += Z[w];
  mu *= (1.f/16.f);
  float var = 0.f;
  #pragma unroll
  for (int w=0; w<16; w++){ float d = Z[w]-mu; var += d*d; }
  var *= (1.f/16.f);
  float rs = rsqrtf(var + 1e-5f);
  float xln[16];
  #pragma unroll
  for (int w=0; w<16; w++) xln[w] = (Z[w]-mu)*rs*g1[16+w] + be1[16+w];
  float h[64];
  for (int j=0;j<64;j++){
    float sacc = b1[64 + j];
    #pragma unroll
    for (int w=0; w<16; w++) sacc += M4[w] * w1[1024 + j*16 + w];
    h[j] = fmaxf(sacc, 0.f);
  }
  float y[16];
  for (int w=0; w<16; w++){
    float sacc = b2[16 + w];
    #pragma unroll
    for (int j=0;j<64;j++) sacc += h[j] * w2[1024 + w*64 + j];
    y[w] = xln[w] + sacc;
  }
  mu = 0.f;
  #pragma unroll
  for (int w=0; w<16; w++) mu += y[w];
  mu *= (1.f/16.f);
  var = 0.f;
  #pragma unroll
  for (int w=0; w<16; w++){ float d = y[w]-mu; var += d*d; }
  var *= (1.f/16.f);
  rs = rsqrtf(var + 1e-5f);
  float o = bh[0];
  #pragma unroll
  for (int w=0; w<16; w++) o += ((y[w]-mu)*rs*g2[16+w] + be2[16+w]) * wh[w];
  out[b] = o;
}

extern "C" void kernel_launch(void* const* d_in, const int* in_sizes, int n_in,
                              void* d_out, int out_size, void* d_ws, size_t ws_size,
                              hipStream_t stream) {
  const float* states = (const float*)d_in[0];
  const float* ra     = (const float*)d_in[1];
  const float* trx    = (const float*)d_in[2];
  const float* tryv   = (const float*)d_in[3];
  const float* w1     = (const float*)d_in[4];
  const float* b1     = (const float*)d_in[5];
  const float* w2     = (const float*)d_in[6];
  const float* b2     = (const float*)d_in[7];
  const float* g1     = (const float*)d_in[8];
  const float* be1    = (const float*)d_in[9];
  const float* g2     = (const float*)d_in[10];
  const float* be2    = (const float*)d_in[11];
  const float* wh     = (const float*)d_in[12];
  const float* bh     = (const float*)d_in[13];
  float* out = (float*)d_out;

  float2* psi = (float2*)d_ws;                                             // 256 MiB
  float* acc  = (float*)((char*)d_ws + (size_t)BSZQ*65536*sizeof(float2)); // 512 x 40
  // Gate table lives in d_out scratch (448 B of 2048 B); qs_tail fully
  // overwrites all 512 outputs afterwards, so this never leaks to the check.
  float* gt = out;

  dim3 g(BSZQ*16);
  qs_prep<<<1, 64, 0, stream>>>(ra, trx, tryv, gt);
  qs_p1<<<g, NT, 0, stream>>>(states, gt, psi, acc);
  qs_p2<<<g, NT, 0, stream>>>(psi, gt);
  qs_p4<<<g, NT, 0, stream>>>(psi, gt, acc);
  qs_p5<<<g, NT, 0, stream>>>(psi, gt, acc);
  qs_tail<<<2, 256, 0, stream>>>(acc, tryv, w1, b1, w2, b2, g1, be1, g2, be2, wh, bh, out);
}

// Round 2
// 632.741 us; speedup vs baseline: 1.3253x; 1.0565x over previous
//
#include <hip/hip_runtime.h>
#include <math.h>

// 16-qubit statevector, 512 batch, float2[512][65536] in d_ws (256 MiB).
// Bit convention: wire w <-> bit (15-w). 4 state passes + tail.
// This round: packed-FP32 VOP3P arithmetic (v_pk_fma_f32 / v_pk_mul_f32).
// Each amp is (re,im) in a VGPR pair; a complex MAC is 2 packed FMAs (one
// with op_sel-swapped source against (-gi,+gi)). Halves the VALU instruction
// count of the dominant butterfly work with ZERO changes to index algebra,
// LDS swizzles, or lane shuffles (all verified in prior rounds).
// Gate/measurement algebra identical to the verified sigma scheme.

#define NT 256
#define ACCS 40
#define BSZQ 512

typedef float v2f __attribute__((ext_vector_type(2)));

__device__ __forceinline__ v2f mk2(float a, float b){ v2f r; r.x = a; r.y = b; return r; }

// ---- packed fp32 primitives (VOP3P) ----
__device__ __forceinline__ v2f pk_mul(v2f a, v2f b){
  v2f d; asm("v_pk_mul_f32 %0, %1, %2" : "=v"(d) : "v"(a), "v"(b)); return d;
}
__device__ __forceinline__ v2f pk_fma(v2f a, v2f b, v2f c){
  v2f d; asm("v_pk_fma_f32 %0, %1, %2, %3" : "=v"(d) : "v"(a), "v"(b), "v"(c)); return d;
}
// a is consumed SWAPPED: lo result uses a.hi, hi result uses a.lo.
__device__ __forceinline__ v2f pk_fma_sw(v2f a, v2f b, v2f c){
  v2f d; asm("v_pk_fma_f32 %0, %1, %2, %3 op_sel:[1,0,0] op_sel_hi:[0,1,1]"
             : "=v"(d) : "v"(a), "v"(b), "v"(c)); return d;
}

struct C2 { float r, i; };
struct G1Q { C2 a, b, c, d; };

__device__ __forceinline__ C2 cmul(C2 x, C2 y){ return C2{ x.r*y.r - x.i*y.i, x.r*y.i + x.i*y.r }; }
__device__ __forceinline__ C2 cadd(C2 x, C2 y){ return C2{ x.r + y.r, x.i + y.i }; }
__device__ __forceinline__ G1Q mkRX(float th){
  float cc = cosf(0.5f*th), ss = sinf(0.5f*th);
  return G1Q{ C2{cc,0.f}, C2{0.f,-ss}, C2{0.f,-ss}, C2{cc,0.f} };
}
__device__ __forceinline__ G1Q mkRY(float th){
  float cc = cosf(0.5f*th), ss = sinf(0.5f*th);
  return G1Q{ C2{cc,0.f}, C2{-ss,0.f}, C2{ss,0.f}, C2{cc,0.f} };
}
__device__ __forceinline__ G1Q gmul(G1Q A, G1Q B){ // A*B, B applied first
  return G1Q{ cadd(cmul(A.a,B.a), cmul(A.b,B.c)),
              cadd(cmul(A.a,B.b), cmul(A.b,B.d)),
              cadd(cmul(A.c,B.a), cmul(A.d,B.c)),
              cadd(cmul(A.c,B.b), cmul(A.d,B.d)) };
}

// Packed gate: splat-real and (-imag,+imag) pairs for each of a,b,c,d.
struct PG1Q { v2f aR, aI, bR, bI, cR, cI, dR, dI; };
__device__ __forceinline__ PG1Q loadPG(const float* __restrict__ gt, int i){
  const float4* p = (const float4*)(gt + i*8);
  float4 u = p[0], w = p[1];
  PG1Q g;
  g.aR = mk2(u.x, u.x); g.aI = mk2(-u.y, u.y);
  g.bR = mk2(u.z, u.z); g.bI = mk2(-u.w, u.w);
  g.cR = mk2(w.x, w.x); g.cI = mk2(-w.y, w.y);
  g.dR = mk2(w.z, w.z); g.dI = mk2(-w.w, w.w);
  return g;
}

// LDS swizzles for p1/p2/p4 staging (proven conflict-minimal).
__device__ __forceinline__ int swzA(int l){ return (l & 0xFF0) | (((l>>4) ^ l) & 15); }
__device__ __forceinline__ int swzB(int l){ return (l & 0xFF0) | (((l>>8) ^ l) & 15); }

// Immediate-pattern lane xor (ds_swizzle BitMode: offset = xor<<10 | and 0x1F).
template<int M>
__device__ __forceinline__ float swzx(float x){
  return __int_as_float(__builtin_amdgcn_ds_swizzle(__float_as_int(x), (M<<10)|0x1F));
}
// Full-wave sum: 5 xor-butterfly steps within 32-lane halves + readlane(0)+readlane(32).
__device__ __forceinline__ float wsum(float x){
  x += swzx<1>(x);
  x += swzx<2>(x);
  x += swzx<4>(x);
  x += swzx<8>(x);
  x += swzx<16>(x);
  return __int_as_float(__builtin_amdgcn_readlane(__float_as_int(x), 0)) +
         __int_as_float(__builtin_amdgcn_readlane(__float_as_int(x), 32));
}

// Butterfly on reg bit q with packed complex math: 8 pk-ops per pair.
__device__ __forceinline__ void greg16p(v2f* v, const PG1Q g, const int q){
  const int bq = 1<<q;
  #pragma unroll
  for (int r=0;r<16;r++){
    if (r & bq) continue;
    v2f a0 = v[r], a1 = v[r|bq];
    v2f t0 = pk_mul(a0, g.aR);
    t0 = pk_fma_sw(a0, g.aI, t0);
    t0 = pk_fma   (a1, g.bR, t0);
    t0 = pk_fma_sw(a1, g.bI, t0);
    v2f t1 = pk_mul(a0, g.cR);
    t1 = pk_fma_sw(a0, g.cI, t1);
    t1 = pk_fma   (a1, g.dR, t1);
    t1 = pk_fma_sw(a1, g.dI, t1);
    v[r] = t0; v[r|bq] = t1;
  }
}
__device__ __forceinline__ void creg16(v2f* v, const int qc, const int qt){
  #pragma unroll
  for (int r=0;r<16;r++){
    if ((r & (1<<qc)) && !(r & (1<<qt))){
      v2f tmp = v[r]; v[r] = v[r|(1<<qt)]; v[r|(1<<qt)] = tmp;
    }
  }
}
__device__ __forceinline__ float xdot16p(const v2f* v, const int m){
  v2f s = pk_mul(v[0], v[m]);
  #pragma unroll
  for (int r=1;r<16;r++) s = pk_fma(v[r], v[r^m], s);
  return s.x + s.y;
}

// ---------------- P0: bake the 14 composed gates (1 thread) ----------------
__global__ void qs_prep(const float* __restrict__ ra, const float* __restrict__ trx,
                        const float* __restrict__ tryv, float* __restrict__ gt){
  if (threadIdx.x != 0) return;
  float trx0 = trx[0];
  G1Q RX0 = mkRX(trx0);
  G1Q g[14];
  g[0]  = gmul(RX0, gmul(mkRY(ra[19]), mkRX(ra[3])));   // p1 alpha q0 (w15)
  g[1]  = mkRX(trx0 + ra[6]);                           // p1 alpha q1
  g[2]  = mkRX(trx0 + ra[9]);                           // p1 alpha q2
  g[3]  = mkRX(trx0 + ra[12]);                          // p1 alpha q3
  g[4]  = mkRX(trx0 + ra[15]);                          // p1 beta q0
  g[5]  = mkRX(trx0 + ra[18]);                          // p1 beta q1
  g[6]  = RX0;                                          // shared
  g[7]  = gmul(RX0, mkRY(ra[4]));                       // p2 A q3 (w4)
  g[8]  = mkRY(ra[1]);                                  // p2 A q2 (w5 RY)
  g[9]  = gmul(RX0, mkRY(ra[7]));                       // p2 B q0 (w3)
  g[10] = gmul(RX0, mkRY(ra[10]));                      // p2 B q1 (w2)
  g[11] = gmul(RX0, mkRY(ra[13]));                      // p2 B q2 (w1)
  g[12] = gmul(RX0, gmul(mkRY(ra[16]), mkRX(ra[0])));   // p2 B q3 (w0)
  g[13] = gmul(mkRX(trx[1]), mkRY(tryv[0]));            // U for p4/p5
  for (int i=0;i<14;i++){
    gt[i*8+0]=g[i].a.r; gt[i*8+1]=g[i].a.i;
    gt[i*8+2]=g[i].b.r; gt[i*8+3]=g[i].b.i;
    gt[i*8+4]=g[i].c.r; gt[i*8+5]=g[i].c.i;
    gt[i*8+6]=g[i].d.r; gt[i*8+7]=g[i].d.i;
  }
}

// ---------------- P1 (L tile): input->complex, random-layer L gates + RX0 ----------------
__global__ __launch_bounds__(NT) void qs_p1(const float* __restrict__ x, const float* __restrict__ gt,
                                            float2* __restrict__ psi, float* __restrict__ acc){
  __shared__ __align__(16) v2f s[4096];
  int b = blockIdx.x >> 4, t = blockIdx.x & 15;
  int tid = threadIdx.x;
  if (t == 0 && tid < ACCS) acc[b*ACCS + tid] = 0.f;
  v2f v[16];
  // phase alpha: regs = bits 0..3, threads = bits 4..11
  const float4* xb = (const float4*)(x + (size_t)b*65536 + t*4096 + tid*16);
  #pragma unroll
  for (int q=0;q<4;q++){
    float4 f = xb[q];
    v[4*q+0] = mk2(f.x, 0.f);
    v[4*q+1] = mk2(f.y, 0.f);
    v[4*q+2] = mk2(f.z, 0.f);
    v[4*q+3] = mk2(f.w, 0.f);
  }
  greg16p(v, loadPG(gt,0), 0);   // w15
  greg16p(v, loadPG(gt,1), 1);   // w14
  greg16p(v, loadPG(gt,2), 2);   // w13
  greg16p(v, loadPG(gt,3), 3);   // w12
  #pragma unroll
  for (int j=0;j<16;j++) s[swzA(j | (tid<<4))] = v[j];
  __syncthreads();
  // phase beta: regs = bits 4..7; tid: b0..3 = bits 0..3, b4..7 = bits 8..11
  #pragma unroll
  for (int r=0;r<16;r++) v[r] = s[swzA((tid&15) | (r<<4) | ((tid>>4)<<8))];
  creg16(v, 1, 0);                       // C(w10->w11)
  creg16(v, 2, 1);                       // C(w9->w10)
  creg16(v, 3, 2);                       // C(w8->w9)
  {                                      // C(w7->w8): ctrl bit8 = tid bit4, tgt bit7 = r3
    bool c8 = (tid & 16);
    #pragma unroll
    for (int r=0;r<8;r++){
      v2f lo = v[r], hi = v[r|8];
      v[r]   = c8 ? hi : lo;
      v[r|8] = c8 ? lo : hi;
    }
  }
  greg16p(v, loadPG(gt,4), 0);   // w11
  greg16p(v, loadPG(gt,5), 1);   // w10
  PG1Q PG6 = loadPG(gt,6);
  greg16p(v, PG6, 2);            // w9
  greg16p(v, PG6, 3);            // w8
  v2f* pbL = (v2f*)(psi + (size_t)b*65536 + t*4096);
  #pragma unroll
  for (int r=0;r<16;r++) pbL[(tid&15) | (r<<4) | ((tid>>4)<<8)] = v[r];
}

// ---------------- P2 (H tile): random-layer H gates + RX0 on wires 0..7 ----------------
__global__ __launch_bounds__(NT) void qs_p2(float2* __restrict__ psi, const float* __restrict__ gt){
  __shared__ __align__(16) v2f s[4096];
  int b = blockIdx.x >> 4, t = blockIdx.x & 15;
  int tid = threadIdx.x;
  v2f v[16];
  v2f* pb = (v2f*)(psi + (size_t)b*65536);
  // phase A: regs = g8..11; tid: b0..3 = g0..3, b4..7 = g12..15
  #pragma unroll
  for (int r=0;r<16;r++)
    v[r] = pb[(tid&15) | (t<<4) | (r<<8) | ((tid>>4)<<12)];
  greg16p(v, loadPG(gt,7), 3);   // w4
  greg16p(v, loadPG(gt,8), 2);   // w5 (RY part)
  creg16(v, 1, 0);               // C(w6->w7)
  creg16(v, 2, 1);               // C(w5->w6)
  PG1Q PG6 = loadPG(gt,6);
  greg16p(v, PG6, 2);            // w5
  greg16p(v, PG6, 1);            // w6
  greg16p(v, PG6, 0);            // w7
  #pragma unroll
  for (int r=0;r<16;r++) s[swzA((tid&15) | (r<<4) | ((tid>>4)<<8))] = v[r];
  __syncthreads();
  // phase B: regs = g12..15; tid: b0..3 = g0..3, b4..7 = g8..11
  #pragma unroll
  for (int r=0;r<16;r++) v[r] = s[swzA((tid&15) | ((tid>>4)<<4) | (r<<8))];
  greg16p(v, loadPG(gt,9), 0);    // w3
  greg16p(v, loadPG(gt,10), 1);   // w2
  greg16p(v, loadPG(gt,11), 2);   // w1
  greg16p(v, loadPG(gt,12), 3);   // w0
  #pragma unroll
  for (int r=0;r<16;r++)
    pb[(tid&15) | (t<<4) | ((tid>>4)<<8) | (r<<12)] = v[r];
}

// ---------------- P4 (H tile on y-frame, T folded into load/store addr) ----------------
// Phases A (y0..3) -> C (y12..15) -> B (y8..11). K as lane-swizzle CNOT in A.
__global__ __launch_bounds__(NT) void qs_p4(float2* __restrict__ psi, const float* __restrict__ gt,
                                            float* __restrict__ acc){
  __shared__ __align__(16) v2f s[4096];
  int b = blockIdx.x >> 4, t = blockIdx.x & 15;
  int tid = threadIdx.x;
  PG1Q U = loadPG(gt, 13);
  v2f* pb = (v2f*)(psi + (size_t)b*65536);
  v2f v[16];
  // ---- phase A: regs y0..3; tid: b0..3 = y12..15, b4..7 = y8..11 ----
  {
    int Y = (tid>>4) | ((tid&15)<<4);          // y8..15
    int XH = Y ^ (Y>>1);                       // x8..15
    int x7 = ((t>>3) ^ Y) & 1;                 // t3 ^ y8
    int runbase = (XH<<8) | (x7<<7) | (((t ^ (t>>1)) & 7) << 4);
    const float4* rp = (const float4*)(pb + runbase);
    v2f tmp[16];
    #pragma unroll
    for (int q=0;q<8;q++){
      float4 f = rp[q];
      tmp[2*q]   = mk2(f.x, f.y);
      tmp[2*q+1] = mk2(f.z, f.w);
    }
    // v[j] = tmp[alpha], j bitk = parity(alpha>>k) (^15 if t0)
    if (t & 1){
      v[15]=tmp[0];  v[14]=tmp[1];  v[12]=tmp[2];  v[13]=tmp[3];
      v[ 8]=tmp[4];  v[ 9]=tmp[5];  v[11]=tmp[6];  v[10]=tmp[7];
      v[ 0]=tmp[8];  v[ 1]=tmp[9];  v[ 3]=tmp[10]; v[ 2]=tmp[11];
      v[ 7]=tmp[12]; v[ 6]=tmp[13]; v[ 4]=tmp[14]; v[ 5]=tmp[15];
    } else {
      v[ 0]=tmp[0];  v[ 1]=tmp[1];  v[ 3]=tmp[2];  v[ 2]=tmp[3];
      v[ 7]=tmp[4];  v[ 6]=tmp[5];  v[ 4]=tmp[6];  v[ 5]=tmp[7];
      v[15]=tmp[8];  v[14]=tmp[9];  v[12]=tmp[10]; v[13]=tmp[11];
      v[ 8]=tmp[12]; v[ 9]=tmp[13]; v[11]=tmp[14]; v[10]=tmp[15];
    }
    // K = C(w15->w0): ctrl y0 (reg bit0), tgt y15 (lane bit3) -> lane-xor swap
    #pragma unroll
    for (int r=1;r<16;r+=2){
      v[r].x = swzx<8>(v[r].x);
      v[r].y = swzx<8>(v[r].y);
    }
    greg16p(v, U, 0); greg16p(v, U, 1); greg16p(v, U, 2); greg16p(v, U, 3); // w15,w14,w13,w12
    #pragma unroll
    for (int j=0;j<16;j++)
      s[swzB(j | ((tid>>4)<<4) | ((tid&15)<<8))] = v[j];
  }
  __syncthreads();
  float Xa, Xb, Xc, Xd;
  // ---- phase C: regs y12..15; tid: b0..3 = y0..3, b4..7 = y8..11 ----
  {
    #pragma unroll
    for (int r=0;r<16;r++)
      v[r] = s[swzB((tid&15) | ((tid>>4)<<4) | (r<<8))];
    greg16p(v, U, 0); greg16p(v, U, 1); greg16p(v, U, 2); greg16p(v, U, 3); // w3,w2,w1,w0
    creg16(v, 3, 2);  // chain1 C(w0->w1)
    creg16(v, 2, 1);  // C(w1->w2)
    creg16(v, 1, 0);  // C(w2->w3)
    Xa = xdot16p(v, 8);   // X_w0 (y15)
    Xb = xdot16p(v, 4);   // X_w1 (y14)
    Xc = xdot16p(v, 2);   // X_w2 (y13)
    v2f XdP = mk2(0.f, 0.f);  // <X_w0 X_w15> = y15 (reg) x y0 (lane bit0)
    #pragma unroll
    for (int r=0;r<16;r++)
      XdP = pk_fma(v[r], mk2(swzx<1>(v[r^8].x), swzx<1>(v[r^8].y)), XdP);
    Xd = XdP.x + XdP.y;
    __syncthreads();
    #pragma unroll
    for (int r=0;r<16;r++)
      s[swzB((tid&15) | ((tid>>4)<<4) | (r<<8))] = v[r];
  }
  __syncthreads();
  // ---- phase B: regs y8..11; tid: b0..3 = y0..3, b4..7 = y12..15 ----
  float Xe, Xf, Xg, Xh;
  {
    #pragma unroll
    for (int r=0;r<16;r++)
      v[r] = s[swzB((tid&15) | (r<<4) | ((tid>>4)<<8))];
    greg16p(v, U, 0); greg16p(v, U, 1); greg16p(v, U, 2); greg16p(v, U, 3); // w7,w6,w5,w4
    {                                  // C(w3->w4): ctrl y12 = tid bit4, tgt y11 = r3
      bool c12 = (tid & 16);
      #pragma unroll
      for (int r=0;r<8;r++){
        v2f lo = v[r], hi = v[r|8];
        v[r]   = c12 ? hi : lo;
        v[r|8] = c12 ? lo : hi;
      }
    }
    creg16(v, 3, 2);  // C(w4->w5)
    creg16(v, 2, 1);  // C(w5->w6)
    creg16(v, 1, 0);  // C(w6->w7)
    v2f XeP = mk2(0.f, 0.f);   // X_w3 (y12 = lane bit4)
    #pragma unroll
    for (int r=0;r<16;r++)
      XeP = pk_fma(v[r], mk2(swzx<16>(v[r].x), swzx<16>(v[r].y)), XeP);
    Xe = XeP.x + XeP.y;
    Xf = xdot16p(v, 8);   // X_w4
    Xg = xdot16p(v, 4);   // X_w5
    Xh = xdot16p(v, 2);   // X_w6
    // store, T folded: g(base|r<<8) = g(base) ^ ((r<<8)^(r<<7))
    int Bs = (tid&15) | (t<<4) | ((tid>>4)<<12);
    int Cs = Bs ^ (Bs>>1);
    #pragma unroll
    for (int r=0;r<16;r++)
      pb[Cs ^ ((r<<8) ^ (r<<7))] = v[r];
  }
  float vals[8] = {Xa, Xb, Xc, Xe, Xf, Xg, Xh, Xd};
  #pragma unroll
  for (int i=0;i<8;i++) vals[i] = wsum(vals[i]);
  if ((tid & 63) == 0){
    float* A = acc + b*ACCS;
    #pragma unroll
    for (int i=0;i<7;i++) atomicAdd(A+25+i, vals[i]);
    atomicAdd(A+32, vals[7]);
  }
}

// ---------------- P5 (L tile, read-only, single-phase, no LDS) ----------------
// Regs = ul4..7 (post-U after 4 greg16); lanes b0..3 = ul0..3, b4..7 = ul8..11.
// S_j (j=0..4) share the single reg-parity class S4l; X dots via lane-xor swizzles.
__global__ __launch_bounds__(NT) void qs_p5(const float2* __restrict__ psi, const float* __restrict__ gt,
                                            float* __restrict__ acc){
  int b = blockIdx.x >> 4, t = blockIdx.x & 15;
  int tid = threadIdx.x;
  PG1Q U = loadPG(gt, 13);
  const v2f* pb = (const v2f*)(psi + (size_t)b*65536);
  v2f v[16];
  // T-unfold gather, strength-reduced: addr(r) = g(Bv) ^ ((r<<4)^(r<<3))
  int Bv = (t<<12) | ((tid>>4)<<8) | (tid&15);
  int Cg = Bv ^ (Bv>>1);
  #pragma unroll
  for (int r=0;r<16;r++)
    v[r] = pb[Cg ^ ((r<<4) ^ (r<<3))];
  greg16p(v, U, 0); greg16p(v, U, 1); greg16p(v, U, 2); greg16p(v, U, 3); // w11..w8
  v2f z2 = mk2(0.f, 0.f);
  v2f totP=z2, S4P=z2, S5P=z2, S6P=z2, S7P=z2;
  #pragma unroll
  for (int r=0;r<16;r++){
    v2f sq = pk_mul(v[r], v[r]);
    totP = totP + sq;
    if (__popc(r)&1)    S4P = S4P + sq;
    if (__popc(r>>1)&1) S5P = S5P + sq;
    if (__popc(r>>2)&1) S6P = S6P + sq;
    if (__popc(r>>3)&1) S7P = S7P + sq;
  }
  float totA = totP.x + totP.y;
  float S4l = S4P.x + S4P.y, S5l = S5P.x + S5P.y;
  float S6l = S6P.x + S6P.y, S7l = S7P.x + S7P.y;
  float S4h = totA - S4l;
  float S0 = (__popc(tid & 0x1F)&1) ? S4h : S4l;   // parity(ul0..8)
  float S1 = (__popc(tid & 0x1E)&1) ? S4h : S4l;   // parity(ul1..8)
  float S2 = (__popc(tid & 0x1C)&1) ? S4h : S4l;   // parity(ul2..8)
  float S3 = (__popc(tid & 0x18)&1) ? S4h : S4l;   // parity(ul3..8)
  bool u8 = (tid & 16);
  float S4 = u8 ? S4h : S4l;                       // parity(ul4..8)
  float S5 = u8 ? totA - S5l : S5l;
  float S6 = u8 ? totA - S6l : S6l;
  float S7 = u8 ? totA - S7l : S7l;
  float S8 = u8 ? totA : 0.f;
  float K9  = (tid & 32) ? totA : 0.f;
  float K10 = (tid & 64) ? totA : 0.f;
  float K11 = (tid & 128)? totA : 0.f;
  float X45 = xdot16p(v,3), X56 = xdot16p(v,6), X67 = xdot16p(v,12);
  v2f X01P=z2, X12P=z2, X23P=z2, X34P=z2, X78P=z2;
  #pragma unroll
  for (int r=0;r<16;r++){
    float vx = v[r].x, vy = v[r].y;
    X01P = pk_fma(v[r], mk2(swzx<3>(vx),  swzx<3>(vy)),  X01P);   // flips ul0,ul1
    X12P = pk_fma(v[r], mk2(swzx<6>(vx),  swzx<6>(vy)),  X12P);   // flips ul1,ul2
    X23P = pk_fma(v[r], mk2(swzx<12>(vx), swzx<12>(vy)), X23P);   // flips ul2,ul3
    X34P = pk_fma(v[r], mk2(swzx<8>(v[r^1].x), swzx<8>(v[r^1].y)), X34P);   // ul3 x ul4
    X78P = pk_fma(v[r], mk2(swzx<16>(v[r^8].x), swzx<16>(v[r^8].y)), X78P); // ul7 x ul8
  }
  float X01 = X01P.x + X01P.y, X12 = X12P.x + X12P.y, X23 = X23P.x + X23P.y;
  float X34 = X34P.x + X34P.y, X78 = X78P.x + X78P.y;
  float vals[21] = {totA, S0,S1,S2,S3,S4,S5,S6,S7,S8, K9,K10,K11,
                    X01,X12,X23,X34,X45,X56,X67,X78};
  #pragma unroll
  for (int i=0;i<21;i++) vals[i] = wsum(vals[i]);
  if ((tid & 63) == 0){
    float* A = acc + b*ACCS;
    atomicAdd(A+0, vals[0]);
    #pragma unroll
    for (int p=0;p<12;p++) atomicAdd(A+1+p, vals[1+p]);
    if (t&1) atomicAdd(A+13, vals[0]);
    if (t&2) atomicAdd(A+14, vals[0]);
    if (t&4) atomicAdd(A+15, vals[0]);
    float zz = vals[0] - 2.f*vals[1];
    if (t&8) zz = -zz;
    atomicAdd(A+16, zz);
    #pragma unroll
    for (int j=0;j<8;j++) atomicAdd(A+17+j, vals[13+j]);
  }
}

// ---------------- Tail (unchanged, verified) ----------------
__global__ __launch_bounds__(256) void qs_tail(const float* __restrict__ acc, const float* __restrict__ tryv,
    const float* __restrict__ w1, const float* __restrict__ b1,
    const float* __restrict__ w2, const float* __restrict__ b2,
    const float* __restrict__ g1, const float* __restrict__ be1,
    const float* __restrict__ g2, const float* __restrict__ be2,
    const float* __restrict__ wh, const float* __restrict__ bh,
    float* __restrict__ out){
  int b = blockIdx.x * 256 + threadIdx.x;
  if (b >= BSZQ) return;
  const float* A = acc + b*ACCS;
  float tot = A[0];
  float inv = 1.f / tot;
  float Z[16], X[16];
  Z[0] = A[16] * inv;
  Z[1] = 1.f - 2.f*A[15]*inv;
  Z[2] = 1.f - 2.f*A[14]*inv;
  Z[3] = 1.f - 2.f*A[13]*inv;
  #pragma unroll
  for (int w=4; w<15; w++) Z[w] = 1.f - 2.f*A[1 + (15-w)]*inv;
  Z[15] = 1.f - 2.f*A[1]*inv;
  #pragma unroll
  for (int w=0; w<7; w++) X[w] = A[25+w]*inv;
  #pragma unroll
  for (int w=7; w<15; w++) X[w] = A[16 + (15-w)]*inv;
  X[15] = A[32]*inv;
  float th = tryv[1];
  float ct = cosf(th), st = sinf(th);
  float M4[16];
  #pragma unroll
  for (int w=0; w<16; w++) M4[w] = ct*Z[w] - st*X[w];
  float mu = 0.f;
  #pragma unroll
  for (int w=0; w<16; w++) mu += Z[w];
  mu *= (1.f/16.f);
  float var = 0.f;
  #pragma unroll
  for (int w=0; w<16; w++){ float d = Z[w]-mu; var += d*d; }
  var *= (1.f/16.f);
  float rs = rsqrtf(var + 1e-5f);
  float xln[16];
  #pragma unroll
  for (int w=0; w<16; w++) xln[w] = (Z[w]-mu)*rs*g1[16+w] + be1[16+w];
  float h[64];
  for (int j=0;j<64;j++){
    float sacc = b1[64 + j];
    #pragma unroll
    for (int w=0; w<16; w++) sacc += M4[w] * w1[1024 + j*16 + w];
    h[j] = fmaxf(sacc, 0.f);
  }
  float y[16];
  for (int w=0; w<16; w++){
    float sacc = b2[16 + w];
    #pragma unroll
    for (int j=0;j<64;j++) sacc += h[j] * w2[1024 + w*64 + j];
    y[w] = xln[w] + sacc;
  }
  mu = 0.f;
  #pragma unroll
  for (int w=0; w<16; w++) mu += y[w];
  mu *= (1.f/16.f);
  var = 0.f;
  #pragma unroll
  for (int w=0; w<16; w++){ float d = y[w]-mu; var += d*d; }
  var *= (1.f/16.f);
  rs = rsqrtf(var + 1e-5f);
  float o = bh[0];
  #pragma unroll
  for (int w=0; w<16; w++) o += ((y[w]-mu)*rs*g2[16+w] + be2[16+w]) * wh[w];
  out[b] = o;
}

extern "C" void kernel_launch(void* const* d_in, const int* in_sizes, int n_in,
                              void* d_out, int out_size, void* d_ws, size_t ws_size,
                              hipStream_t stream) {
  const float* states = (const float*)d_in[0];
  const float* ra     = (const float*)d_in[1];
  const float* trx    = (const float*)d_in[2];
  const float* tryv   = (const float*)d_in[3];
  const float* w1     = (const float*)d_in[4];
  const float* b1     = (const float*)d_in[5];
  const float* w2     = (const float*)d_in[6];
  const float* b2     = (const float*)d_in[7];
  const float* g1     = (const float*)d_in[8];
  const float* be1    = (const float*)d_in[9];
  const float* g2     = (const float*)d_in[10];
  const float* be2    = (const float*)d_in[11];
  const float* wh     = (const float*)d_in[12];
  const float* bh     = (const float*)d_in[13];
  float* out = (float*)d_out;

  float2* psi = (float2*)d_ws;                                             // 256 MiB
  float* acc  = (float*)((char*)d_ws + (size_t)BSZQ*65536*sizeof(float2)); // 512 x 40
  // Gate table lives in d_out scratch (448 B of 2048 B); qs_tail fully
  // overwrites all 512 outputs afterwards, so this never leaks to the check.
  float* gt = out;

  dim3 g(BSZQ*16);
  qs_prep<<<1, 64, 0, stream>>>(ra, trx, tryv, gt);
  qs_p1<<<g, NT, 0, stream>>>(states, gt, psi, acc);
  qs_p2<<<g, NT, 0, stream>>>(psi, gt);
  qs_p4<<<g, NT, 0, stream>>>(psi, gt, acc);
  qs_p5<<<g, NT, 0, stream>>>(psi, gt, acc);
  qs_tail<<<2, 256, 0, stream>>>(acc, tryv, w1, b1, w2, b2, g1, be1, g2, be2, wh, bh, out);
}

// Round 4
// 539.677 us; speedup vs baseline: 1.5538x; 1.1724x over previous
//
#include <hip/hip_runtime.h>
#include <math.h>

// 16-qubit statevector, 512 batch. Inter-pass psi now FP16 (half2 per amp):
// uint[512][65536] in d_ws = 128 MiB -> fully Infinity-Cache resident, and
// every inter-pass byte halved. All gate/measurement math stays fp32 in
// registers (packed VOP3P); only global load/store sites convert.
// Store = v_cvt_pkrtz_f16_f32 (rtz scale bias cancels in normalized measures);
// load = 2x v_cvt_f32_f16. Index algebra / LDS swizzles / shuffles unchanged
// from the verified sigma scheme.

#define NT 256
#define ACCS 40
#define BSZQ 512

typedef float v2f __attribute__((ext_vector_type(2)));
typedef __fp16 h2t __attribute__((ext_vector_type(2)));

__device__ __forceinline__ v2f mk2(float a, float b){ v2f r; r.x = a; r.y = b; return r; }

// fp32 pair -> packed fp16 (single v_cvt_pkrtz_f16_f32)
__device__ __forceinline__ unsigned int f2h(v2f a){
  h2t h = __builtin_amdgcn_cvt_pkrtz(a.x, a.y);
  return *(unsigned int*)&h;
}
// packed fp16 -> fp32 pair (2x v_cvt_f32_f16)
__device__ __forceinline__ v2f h2f(unsigned int u){
  h2t h = *(h2t*)&u;
  return mk2((float)h.x, (float)h.y);
}

// ---- packed fp32 primitives (VOP3P) ----
__device__ __forceinline__ v2f pk_mul(v2f a, v2f b){
  v2f d; asm("v_pk_mul_f32 %0, %1, %2" : "=v"(d) : "v"(a), "v"(b)); return d;
}
__device__ __forceinline__ v2f pk_fma(v2f a, v2f b, v2f c){
  v2f d; asm("v_pk_fma_f32 %0, %1, %2, %3" : "=v"(d) : "v"(a), "v"(b), "v"(c)); return d;
}
// a is consumed SWAPPED: lo result uses a.hi, hi result uses a.lo.
__device__ __forceinline__ v2f pk_fma_sw(v2f a, v2f b, v2f c){
  v2f d; asm("v_pk_fma_f32 %0, %1, %2, %3 op_sel:[1,0,0] op_sel_hi:[0,1,1]"
             : "=v"(d) : "v"(a), "v"(b), "v"(c)); return d;
}

struct C2 { float r, i; };
struct G1Q { C2 a, b, c, d; };

__device__ __forceinline__ C2 cmul(C2 x, C2 y){ return C2{ x.r*y.r - x.i*y.i, x.r*y.i + x.i*y.r }; }
__device__ __forceinline__ C2 cadd(C2 x, C2 y){ return C2{ x.r + y.r, x.i + y.i }; }
__device__ __forceinline__ G1Q mkRX(float th){
  float cc = cosf(0.5f*th), ss = sinf(0.5f*th);
  return G1Q{ C2{cc,0.f}, C2{0.f,-ss}, C2{0.f,-ss}, C2{cc,0.f} };
}
__device__ __forceinline__ G1Q mkRY(float th){
  float cc = cosf(0.5f*th), ss = sinf(0.5f*th);
  return G1Q{ C2{cc,0.f}, C2{-ss,0.f}, C2{ss,0.f}, C2{cc,0.f} };
}
__device__ __forceinline__ G1Q gmul(G1Q A, G1Q B){ // A*B, B applied first
  return G1Q{ cadd(cmul(A.a,B.a), cmul(A.b,B.c)),
              cadd(cmul(A.a,B.b), cmul(A.b,B.d)),
              cadd(cmul(A.c,B.a), cmul(A.d,B.c)),
              cadd(cmul(A.c,B.b), cmul(A.d,B.d)) };
}

// Packed gate: splat-real and (-imag,+imag) pairs for each of a,b,c,d.
struct PG1Q { v2f aR, aI, bR, bI, cR, cI, dR, dI; };
__device__ __forceinline__ PG1Q loadPG(const float* __restrict__ gt, int i){
  const float4* p = (const float4*)(gt + i*8);
  float4 u = p[0], w = p[1];
  PG1Q g;
  g.aR = mk2(u.x, u.x); g.aI = mk2(-u.y, u.y);
  g.bR = mk2(u.z, u.z); g.bI = mk2(-u.w, u.w);
  g.cR = mk2(w.x, w.x); g.cI = mk2(-w.y, w.y);
  g.dR = mk2(w.z, w.z); g.dI = mk2(-w.w, w.w);
  return g;
}

// LDS swizzles for p1/p2/p4 staging (proven conflict-minimal).
__device__ __forceinline__ int swzA(int l){ return (l & 0xFF0) | (((l>>4) ^ l) & 15); }
__device__ __forceinline__ int swzB(int l){ return (l & 0xFF0) | (((l>>8) ^ l) & 15); }

// Immediate-pattern lane xor (ds_swizzle BitMode: offset = xor<<10 | and 0x1F).
template<int M>
__device__ __forceinline__ float swzx(float x){
  return __int_as_float(__builtin_amdgcn_ds_swizzle(__float_as_int(x), (M<<10)|0x1F));
}
// Full-wave sum: 5 xor-butterfly steps within 32-lane halves + readlane(0)+readlane(32).
__device__ __forceinline__ float wsum(float x){
  x += swzx<1>(x);
  x += swzx<2>(x);
  x += swzx<4>(x);
  x += swzx<8>(x);
  x += swzx<16>(x);
  return __int_as_float(__builtin_amdgcn_readlane(__float_as_int(x), 0)) +
         __int_as_float(__builtin_amdgcn_readlane(__float_as_int(x), 32));
}

// Butterfly on reg bit q with packed complex math: 8 pk-ops per pair.
__device__ __forceinline__ void greg16p(v2f* v, const PG1Q g, const int q){
  const int bq = 1<<q;
  #pragma unroll
  for (int r=0;r<16;r++){
    if (r & bq) continue;
    v2f a0 = v[r], a1 = v[r|bq];
    v2f t0 = pk_mul(a0, g.aR);
    t0 = pk_fma_sw(a0, g.aI, t0);
    t0 = pk_fma   (a1, g.bR, t0);
    t0 = pk_fma_sw(a1, g.bI, t0);
    v2f t1 = pk_mul(a0, g.cR);
    t1 = pk_fma_sw(a0, g.cI, t1);
    t1 = pk_fma   (a1, g.dR, t1);
    t1 = pk_fma_sw(a1, g.dI, t1);
    v[r] = t0; v[r|bq] = t1;
  }
}
__device__ __forceinline__ void creg16(v2f* v, const int qc, const int qt){
  #pragma unroll
  for (int r=0;r<16;r++){
    if ((r & (1<<qc)) && !(r & (1<<qt))){
      v2f tmp = v[r]; v[r] = v[r|(1<<qt)]; v[r|(1<<qt)] = tmp;
    }
  }
}
__device__ __forceinline__ float xdot16p(const v2f* v, const int m){
  v2f s = pk_mul(v[0], v[m]);
  #pragma unroll
  for (int r=1;r<16;r++) s = pk_fma(v[r], v[r^m], s);
  return s.x + s.y;
}

// ---------------- P0: bake the 14 composed gates (1 thread) ----------------
__global__ void qs_prep(const float* __restrict__ ra, const float* __restrict__ trx,
                        const float* __restrict__ tryv, float* __restrict__ gt){
  if (threadIdx.x != 0) return;
  float trx0 = trx[0];
  G1Q RX0 = mkRX(trx0);
  G1Q g[14];
  g[0]  = gmul(RX0, gmul(mkRY(ra[19]), mkRX(ra[3])));   // p1 alpha q0 (w15)
  g[1]  = mkRX(trx0 + ra[6]);                           // p1 alpha q1
  g[2]  = mkRX(trx0 + ra[9]);                           // p1 alpha q2
  g[3]  = mkRX(trx0 + ra[12]);                          // p1 alpha q3
  g[4]  = mkRX(trx0 + ra[15]);                          // p1 beta q0
  g[5]  = mkRX(trx0 + ra[18]);                          // p1 beta q1
  g[6]  = RX0;                                          // shared
  g[7]  = gmul(RX0, mkRY(ra[4]));                       // p2 A q3 (w4)
  g[8]  = mkRY(ra[1]);                                  // p2 A q2 (w5 RY)
  g[9]  = gmul(RX0, mkRY(ra[7]));                       // p2 B q0 (w3)
  g[10] = gmul(RX0, mkRY(ra[10]));                      // p2 B q1 (w2)
  g[11] = gmul(RX0, mkRY(ra[13]));                      // p2 B q2 (w1)
  g[12] = gmul(RX0, gmul(mkRY(ra[16]), mkRX(ra[0])));   // p2 B q3 (w0)
  g[13] = gmul(mkRX(trx[1]), mkRY(tryv[0]));            // U for p4/p5
  for (int i=0;i<14;i++){
    gt[i*8+0]=g[i].a.r; gt[i*8+1]=g[i].a.i;
    gt[i*8+2]=g[i].b.r; gt[i*8+3]=g[i].b.i;
    gt[i*8+4]=g[i].c.r; gt[i*8+5]=g[i].c.i;
    gt[i*8+6]=g[i].d.r; gt[i*8+7]=g[i].d.i;
  }
}

// ---------------- P1 (L tile): input->complex, random-layer L gates + RX0 ----------------
__global__ __launch_bounds__(NT) void qs_p1(const float* __restrict__ x, const float* __restrict__ gt,
                                            unsigned int* __restrict__ psi, float* __restrict__ acc){
  __shared__ __align__(16) v2f s[4096];
  int b = blockIdx.x >> 4, t = blockIdx.x & 15;
  int tid = threadIdx.x;
  if (t == 0 && tid < ACCS) acc[b*ACCS + tid] = 0.f;
  v2f v[16];
  // phase alpha: regs = bits 0..3, threads = bits 4..11
  const float4* xb = (const float4*)(x + (size_t)b*65536 + t*4096 + tid*16);
  #pragma unroll
  for (int q=0;q<4;q++){
    float4 f = xb[q];
    v[4*q+0] = mk2(f.x, 0.f);
    v[4*q+1] = mk2(f.y, 0.f);
    v[4*q+2] = mk2(f.z, 0.f);
    v[4*q+3] = mk2(f.w, 0.f);
  }
  greg16p(v, loadPG(gt,0), 0);   // w15
  greg16p(v, loadPG(gt,1), 1);   // w14
  greg16p(v, loadPG(gt,2), 2);   // w13
  greg16p(v, loadPG(gt,3), 3);   // w12
  #pragma unroll
  for (int j=0;j<16;j++) s[swzA(j | (tid<<4))] = v[j];
  __syncthreads();
  // phase beta: regs = bits 4..7; tid: b0..3 = bits 0..3, b4..7 = bits 8..11
  #pragma unroll
  for (int r=0;r<16;r++) v[r] = s[swzA((tid&15) | (r<<4) | ((tid>>4)<<8))];
  creg16(v, 1, 0);                       // C(w10->w11)
  creg16(v, 2, 1);                       // C(w9->w10)
  creg16(v, 3, 2);                       // C(w8->w9)
  {                                      // C(w7->w8): ctrl bit8 = tid bit4, tgt bit7 = r3
    bool c8 = (tid & 16);
    #pragma unroll
    for (int r=0;r<8;r++){
      v2f lo = v[r], hi = v[r|8];
      v[r]   = c8 ? hi : lo;
      v[r|8] = c8 ? lo : hi;
    }
  }
  greg16p(v, loadPG(gt,4), 0);   // w11
  greg16p(v, loadPG(gt,5), 1);   // w10
  PG1Q PG6 = loadPG(gt,6);
  greg16p(v, PG6, 2);            // w9
  greg16p(v, PG6, 3);            // w8
  unsigned int* pbL = psi + (size_t)b*65536 + t*4096;
  #pragma unroll
  for (int r=0;r<16;r++) pbL[(tid&15) | (r<<4) | ((tid>>4)<<8)] = f2h(v[r]);
}

// ---------------- P2 (H tile): random-layer H gates + RX0 on wires 0..7 ----------------
__global__ __launch_bounds__(NT) void qs_p2(unsigned int* __restrict__ psi, const float* __restrict__ gt){
  __shared__ __align__(16) v2f s[4096];
  int b = blockIdx.x >> 4, t = blockIdx.x & 15;
  int tid = threadIdx.x;
  v2f v[16];
  unsigned int* pb = psi + (size_t)b*65536;
  // phase A: regs = g8..11; tid: b0..3 = g0..3, b4..7 = g12..15
  #pragma unroll
  for (int r=0;r<16;r++)
    v[r] = h2f(pb[(tid&15) | (t<<4) | (r<<8) | ((tid>>4)<<12)]);
  greg16p(v, loadPG(gt,7), 3);   // w4
  greg16p(v, loadPG(gt,8), 2);   // w5 (RY part)
  creg16(v, 1, 0);               // C(w6->w7)
  creg16(v, 2, 1);               // C(w5->w6)
  PG1Q PG6 = loadPG(gt,6);
  greg16p(v, PG6, 2);            // w5
  greg16p(v, PG6, 1);            // w6
  greg16p(v, PG6, 0);            // w7
  #pragma unroll
  for (int r=0;r<16;r++) s[swzA((tid&15) | (r<<4) | ((tid>>4)<<8))] = v[r];
  __syncthreads();
  // phase B: regs = g12..15; tid: b0..3 = g0..3, b4..7 = g8..11
  #pragma unroll
  for (int r=0;r<16;r++) v[r] = s[swzA((tid&15) | ((tid>>4)<<4) | (r<<8))];
  greg16p(v, loadPG(gt,9), 0);    // w3
  greg16p(v, loadPG(gt,10), 1);   // w2
  greg16p(v, loadPG(gt,11), 2);   // w1
  greg16p(v, loadPG(gt,12), 3);   // w0
  #pragma unroll
  for (int r=0;r<16;r++)
    pb[(tid&15) | (t<<4) | ((tid>>4)<<8) | (r<<12)] = f2h(v[r]);
}

// ---------------- P4 (H tile on y-frame, T folded into load/store addr) ----------------
// Phases A (y0..3) -> C (y12..15) -> B (y8..11). K as lane-swizzle CNOT in A.
__global__ __launch_bounds__(NT) void qs_p4(unsigned int* __restrict__ psi, const float* __restrict__ gt,
                                            float* __restrict__ acc){
  __shared__ __align__(16) v2f s[4096];
  int b = blockIdx.x >> 4, t = blockIdx.x & 15;
  int tid = threadIdx.x;
  PG1Q U = loadPG(gt, 13);
  unsigned int* pb = psi + (size_t)b*65536;
  v2f v[16];
  // ---- phase A: regs y0..3; tid: b0..3 = y12..15, b4..7 = y8..11 ----
  {
    int Y = (tid>>4) | ((tid&15)<<4);          // y8..15
    int XH = Y ^ (Y>>1);                       // x8..15
    int x7 = ((t>>3) ^ Y) & 1;                 // t3 ^ y8
    int runbase = (XH<<8) | (x7<<7) | (((t ^ (t>>1)) & 7) << 4);
    const uint4* rp = (const uint4*)(pb + runbase);
    v2f tmp[16];
    #pragma unroll
    for (int q=0;q<4;q++){
      uint4 u = rp[q];
      tmp[4*q+0] = h2f(u.x);
      tmp[4*q+1] = h2f(u.y);
      tmp[4*q+2] = h2f(u.z);
      tmp[4*q+3] = h2f(u.w);
    }
    // v[j] = tmp[alpha], j bitk = parity(alpha>>k) (^15 if t0)
    if (t & 1){
      v[15]=tmp[0];  v[14]=tmp[1];  v[12]=tmp[2];  v[13]=tmp[3];
      v[ 8]=tmp[4];  v[ 9]=tmp[5];  v[11]=tmp[6];  v[10]=tmp[7];
      v[ 0]=tmp[8];  v[ 1]=tmp[9];  v[ 3]=tmp[10]; v[ 2]=tmp[11];
      v[ 7]=tmp[12]; v[ 6]=tmp[13]; v[ 4]=tmp[14]; v[ 5]=tmp[15];
    } else {
      v[ 0]=tmp[0];  v[ 1]=tmp[1];  v[ 3]=tmp[2];  v[ 2]=tmp[3];
      v[ 7]=tmp[4];  v[ 6]=tmp[5];  v[ 4]=tmp[6];  v[ 5]=tmp[7];
      v[15]=tmp[8];  v[14]=tmp[9];  v[12]=tmp[10]; v[13]=tmp[11];
      v[ 8]=tmp[12]; v[ 9]=tmp[13]; v[11]=tmp[14]; v[10]=tmp[15];
    }
    // K = C(w15->w0): ctrl y0 (reg bit0), tgt y15 (lane bit3) -> lane-xor swap
    #pragma unroll
    for (int r=1;r<16;r+=2){
      v[r].x = swzx<8>(v[r].x);
      v[r].y = swzx<8>(v[r].y);
    }
    greg16p(v, U, 0); greg16p(v, U, 1); greg16p(v, U, 2); greg16p(v, U, 3); // w15,w14,w13,w12
    #pragma unroll
    for (int j=0;j<16;j++)
      s[swzB(j | ((tid>>4)<<4) | ((tid&15)<<8))] = v[j];
  }
  __syncthreads();
  float Xa, Xb, Xc, Xd;
  // ---- phase C: regs y12..15; tid: b0..3 = y0..3, b4..7 = y8..11 ----
  {
    #pragma unroll
    for (int r=0;r<16;r++)
      v[r] = s[swzB((tid&15) | ((tid>>4)<<4) | (r<<8))];
    greg16p(v, U, 0); greg16p(v, U, 1); greg16p(v, U, 2); greg16p(v, U, 3); // w3,w2,w1,w0
    creg16(v, 3, 2);  // chain1 C(w0->w1)
    creg16(v, 2, 1);  // C(w1->w2)
    creg16(v, 1, 0);  // C(w2->w3)
    Xa = xdot16p(v, 8);   // X_w0 (y15)
    Xb = xdot16p(v, 4);   // X_w1 (y14)
    Xc = xdot16p(v, 2);   // X_w2 (y13)
    v2f XdP = mk2(0.f, 0.f);  // <X_w0 X_w15> = y15 (reg) x y0 (lane bit0)
    #pragma unroll
    for (int r=0;r<16;r++)
      XdP = pk_fma(v[r], mk2(swzx<1>(v[r^8].x), swzx<1>(v[r^8].y)), XdP);
    Xd = XdP.x + XdP.y;
    __syncthreads();
    #pragma unroll
    for (int r=0;r<16;r++)
      s[swzB((tid&15) | ((tid>>4)<<4) | (r<<8))] = v[r];
  }
  __syncthreads();
  // ---- phase B: regs y8..11; tid: b0..3 = y0..3, b4..7 = y12..15 ----
  float Xe, Xf, Xg, Xh;
  {
    #pragma unroll
    for (int r=0;r<16;r++)
      v[r] = s[swzB((tid&15) | (r<<4) | ((tid>>4)<<8))];
    greg16p(v, U, 0); greg16p(v, U, 1); greg16p(v, U, 2); greg16p(v, U, 3); // w7,w6,w5,w4
    {                                  // C(w3->w4): ctrl y12 = tid bit4, tgt y11 = r3
      bool c12 = (tid & 16);
      #pragma unroll
      for (int r=0;r<8;r++){
        v2f lo = v[r], hi = v[r|8];
        v[r]   = c12 ? hi : lo;
        v[r|8] = c12 ? lo : hi;
      }
    }
    creg16(v, 3, 2);  // C(w4->w5)
    creg16(v, 2, 1);  // C(w5->w6)
    creg16(v, 1, 0);  // C(w6->w7)
    v2f XeP = mk2(0.f, 0.f);   // X_w3 (y12 = lane bit4)
    #pragma unroll
    for (int r=0;r<16;r++)
      XeP = pk_fma(v[r], mk2(swzx<16>(v[r].x), swzx<16>(v[r].y)), XeP);
    Xe = XeP.x + XeP.y;
    Xf = xdot16p(v, 8);   // X_w4
    Xg = xdot16p(v, 4);   // X_w5
    Xh = xdot16p(v, 2);   // X_w6
    // store, T folded: g(base|r<<8) = g(base) ^ ((r<<8)^(r<<7))
    int Bs = (tid&15) | (t<<4) | ((tid>>4)<<12);
    int Cs = Bs ^ (Bs>>1);
    #pragma unroll
    for (int r=0;r<16;r++)
      pb[Cs ^ ((r<<8) ^ (r<<7))] = f2h(v[r]);
  }
  float vals[8] = {Xa, Xb, Xc, Xe, Xf, Xg, Xh, Xd};
  #pragma unroll
  for (int i=0;i<8;i++) vals[i] = wsum(vals[i]);
  if ((tid & 63) == 0){
    float* A = acc + b*ACCS;
    #pragma unroll
    for (int i=0;i<7;i++) atomicAdd(A+25+i, vals[i]);
    atomicAdd(A+32, vals[7]);
  }
}

// ---------------- P5 (L tile, read-only, single-phase, no LDS) ----------------
// Regs = ul4..7 (post-U after 4 greg16); lanes b0..3 = ul0..3, b4..7 = ul8..11.
// S_j (j=0..4) share the single reg-parity class S4l; X dots via lane-xor swizzles.
__global__ __launch_bounds__(NT) void qs_p5(const unsigned int* __restrict__ psi, const float* __restrict__ gt,
                                            float* __restrict__ acc){
  int b = blockIdx.x >> 4, t = blockIdx.x & 15;
  int tid = threadIdx.x;
  PG1Q U = loadPG(gt, 13);
  const unsigned int* pb = psi + (size_t)b*65536;
  v2f v[16];
  // T-unfold gather, strength-reduced: addr(r) = g(Bv) ^ ((r<<4)^(r<<3))
  int Bv = (t<<12) | ((tid>>4)<<8) | (tid&15);
  int Cg = Bv ^ (Bv>>1);
  #pragma unroll
  for (int r=0;r<16;r++)
    v[r] = h2f(pb[Cg ^ ((r<<4) ^ (r<<3))]);
  greg16p(v, U, 0); greg16p(v, U, 1); greg16p(v, U, 2); greg16p(v, U, 3); // w11..w8
  v2f z2 = mk2(0.f, 0.f);
  v2f totP=z2, S4P=z2, S5P=z2, S6P=z2, S7P=z2;
  #pragma unroll
  for (int r=0;r<16;r++){
    v2f sq = pk_mul(v[r], v[r]);
    totP = totP + sq;
    if (__popc(r)&1)    S4P = S4P + sq;
    if (__popc(r>>1)&1) S5P = S5P + sq;
    if (__popc(r>>2)&1) S6P = S6P + sq;
    if (__popc(r>>3)&1) S7P = S7P + sq;
  }
  float totA = totP.x + totP.y;
  float S4l = S4P.x + S4P.y, S5l = S5P.x + S5P.y;
  float S6l = S6P.x + S6P.y, S7l = S7P.x + S7P.y;
  float S4h = totA - S4l;
  float S0 = (__popc(tid & 0x1F)&1) ? S4h : S4l;   // parity(ul0..8)
  float S1 = (__popc(tid & 0x1E)&1) ? S4h : S4l;   // parity(ul1..8)
  float S2 = (__popc(tid & 0x1C)&1) ? S4h : S4l;   // parity(ul2..8)
  float S3 = (__popc(tid & 0x18)&1) ? S4h : S4l;   // parity(ul3..8)
  bool u8 = (tid & 16);
  float S4 = u8 ? S4h : S4l;                       // parity(ul4..8)
  float S5 = u8 ? totA - S5l : S5l;
  float S6 = u8 ? totA - S6l : S6l;
  float S7 = u8 ? totA - S7l : S7l;
  float S8 = u8 ? totA : 0.f;
  float K9  = (tid & 32) ? totA : 0.f;
  float K10 = (tid & 64) ? totA : 0.f;
  float K11 = (tid & 128)? totA : 0.f;
  float X45 = xdot16p(v,3), X56 = xdot16p(v,6), X67 = xdot16p(v,12);
  v2f X01P=z2, X12P=z2, X23P=z2, X34P=z2, X78P=z2;
  #pragma unroll
  for (int r=0;r<16;r++){
    float vx = v[r].x, vy = v[r].y;
    X01P = pk_fma(v[r], mk2(swzx<3>(vx),  swzx<3>(vy)),  X01P);   // flips ul0,ul1
    X12P = pk_fma(v[r], mk2(swzx<6>(vx),  swzx<6>(vy)),  X12P);   // flips ul1,ul2
    X23P = pk_fma(v[r], mk2(swzx<12>(vx), swzx<12>(vy)), X23P);   // flips ul2,ul3
    X34P = pk_fma(v[r], mk2(swzx<8>(v[r^1].x), swzx<8>(v[r^1].y)), X34P);   // ul3 x ul4
    X78P = pk_fma(v[r], mk2(swzx<16>(v[r^8].x), swzx<16>(v[r^8].y)), X78P); // ul7 x ul8
  }
  float X01 = X01P.x + X01P.y, X12 = X12P.x + X12P.y, X23 = X23P.x + X23P.y;
  float X34 = X34P.x + X34P.y, X78 = X78P.x + X78P.y;
  float vals[21] = {totA, S0,S1,S2,S3,S4,S5,S6,S7,S8, K9,K10,K11,
                    X01,X12,X23,X34,X45,X56,X67,X78};
  #pragma unroll
  for (int i=0;i<21;i++) vals[i] = wsum(vals[i]);
  if ((tid & 63) == 0){
    float* A = acc + b*ACCS;
    atomicAdd(A+0, vals[0]);
    #pragma unroll
    for (int p=0;p<12;p++) atomicAdd(A+1+p, vals[1+p]);
    if (t&1) atomicAdd(A+13, vals[0]);
    if (t&2) atomicAdd(A+14, vals[0]);
    if (t&4) atomicAdd(A+15, vals[0]);
    float zz = vals[0] - 2.f*vals[1];
    if (t&8) zz = -zz;
    atomicAdd(A+16, zz);
    #pragma unroll
    for (int j=0;j<8;j++) atomicAdd(A+17+j, vals[13+j]);
  }
}

// ---------------- Tail (unchanged, verified) ----------------
__global__ __launch_bounds__(256) void qs_tail(const float* __restrict__ acc, const float* __restrict__ tryv,
    const float* __restrict__ w1, const float* __restrict__ b1,
    const float* __restrict__ w2, const float* __restrict__ b2,
    const float* __restrict__ g1, const float* __restrict__ be1,
    const float* __restrict__ g2, const float* __restrict__ be2,
    const float* __restrict__ wh, const float* __restrict__ bh,
    float* __restrict__ out){
  int b = blockIdx.x * 256 + threadIdx.x;
  if (b >= BSZQ) return;
  const float* A = acc + b*ACCS;
  float tot = A[0];
  float inv = 1.f / tot;
  float Z[16], X[16];
  Z[0] = A[16] * inv;
  Z[1] = 1.f - 2.f*A[15]*inv;
  Z[2] = 1.f - 2.f*A[14]*inv;
  Z[3] = 1.f - 2.f*A[13]*inv;
  #pragma unroll
  for (int w=4; w<15; w++) Z[w] = 1.f - 2.f*A[1 + (15-w)]*inv;
  Z[15] = 1.f - 2.f*A[1]*inv;
  #pragma unroll
  for (int w=0; w<7; w++) X[w] = A[25+w]*inv;
  #pragma unroll
  for (int w=7; w<15; w++) X[w] = A[16 + (15-w)]*inv;
  X[15] = A[32]*inv;
  float th = tryv[1];
  float ct = cosf(th), st = sinf(th);
  float M4[16];
  #pragma unroll
  for (int w=0; w<16; w++) M4[w] = ct*Z[w] - st*X[w];
  float mu = 0.f;
  #pragma unroll
  for (int w=0; w<16; w++) mu += Z[w];
  mu *= (1.f/16.f);
  float var = 0.f;
  #pragma unroll
  for (int w=0; w<16; w++){ float d = Z[w]-mu; var += d*d; }
  var *= (1.f/16.f);
  float rs = rsqrtf(var + 1e-5f);
  float xln[16];
  #pragma unroll
  for (int w=0; w<16; w++) xln[w] = (Z[w]-mu)*rs*g1[16+w] + be1[16+w];
  float h[64];
  for (int j=0;j<64;j++){
    float sacc = b1[64 + j];
    #pragma unroll
    for (int w=0; w<16; w++) sacc += M4[w] * w1[1024 + j*16 + w];
    h[j] = fmaxf(sacc, 0.f);
  }
  float y[16];
  for (int w=0; w<16; w++){
    float sacc = b2[16 + w];
    #pragma unroll
    for (int j=0;j<64;j++) sacc += h[j] * w2[1024 + w*64 + j];
    y[w] = xln[w] + sacc;
  }
  mu = 0.f;
  #pragma unroll
  for (int w=0; w<16; w++) mu += y[w];
  mu *= (1.f/16.f);
  var = 0.f;
  #pragma unroll
  for (int w=0; w<16; w++){ float d = y[w]-mu; var += d*d; }
  var *= (1.f/16.f);
  rs = rsqrtf(var + 1e-5f);
  float o = bh[0];
  #pragma unroll
  for (int w=0; w<16; w++) o += ((y[w]-mu)*rs*g2[16+w] + be2[16+w]) * wh[w];
  out[b] = o;
}

extern "C" void kernel_launch(void* const* d_in, const int* in_sizes, int n_in,
                              void* d_out, int out_size, void* d_ws, size_t ws_size,
                              hipStream_t stream) {
  const float* states = (const float*)d_in[0];
  const float* ra     = (const float*)d_in[1];
  const float* trx    = (const float*)d_in[2];
  const float* tryv   = (const float*)d_in[3];
  const float* w1     = (const float*)d_in[4];
  const float* b1     = (const float*)d_in[5];
  const float* w2     = (const float*)d_in[6];
  const float* b2     = (const float*)d_in[7];
  const float* g1     = (const float*)d_in[8];
  const float* be1    = (const float*)d_in[9];
  const float* g2     = (const float*)d_in[10];
  const float* be2    = (const float*)d_in[11];
  const float* wh     = (const float*)d_in[12];
  const float* bh     = (const float*)d_in[13];
  float* out = (float*)d_out;

  unsigned int* psi = (unsigned int*)d_ws;                                 // 128 MiB (fp16 amps)
  float* acc  = (float*)((char*)d_ws + (size_t)BSZQ*65536*sizeof(float2)); // keep old offset (512 x 40)
  // Gate table lives in d_out scratch (448 B of 2048 B); qs_tail fully
  // overwrites all 512 outputs afterwards, so this never leaks to the check.
  float* gt = out;

  dim3 g(BSZQ*16);
  qs_prep<<<1, 64, 0, stream>>>(ra, trx, tryv, gt);
  qs_p1<<<g, NT, 0, stream>>>(states, gt, psi, acc);
  qs_p2<<<g, NT, 0, stream>>>(psi, gt);
  qs_p4<<<g, NT, 0, stream>>>(psi, gt, acc);
  qs_p5<<<g, NT, 0, stream>>>(psi, gt, acc);
  qs_tail<<<2, 256, 0, stream>>>(acc, tryv, w1, b1, w2, b2, g1, be1, g2, be2, wh, bh, out);
}